// Round 5
// baseline (2284.606 us; speedup 1.0000x reference)
//
#include <hip/hip_runtime.h>
#include <hip/hip_bf16.h>

// Problem constants: B=64, T=512, I=1024, H=1024 (fp32 in/out).
#define BB_   64
#define TT_   512
#define II_   1024
#define HH_   1024

typedef _Float16 half8  __attribute__((ext_vector_type(8)));
typedef _Float16 half4v __attribute__((ext_vector_type(4)));
typedef float    f32x4  __attribute__((ext_vector_type(4)));

// tanh(x) = 1 - 2/(exp(2x)+1); clamp |x|<=16 (tanh saturates; avoids inf/inf).
// v_exp_f32 + v_rcp_f32: ~6 ops vs ocml tanhf's ~300cy chain. abs err ~1e-7,
// invisible vs the f16 comm rounding (absmax 0.0039, r1/r3).
__device__ __forceinline__ float fast_tanh(float x) {
    float t = fminf(fmaxf(x, -16.f), 16.f);
    float e = __builtin_amdgcn_exp2f(t * 2.885390082f);   // exp(2t)
    return 1.f - 2.f * __builtin_amdgcn_rcpf(e + 1.f);
}

// ---------------------------------------------------------------------------
// Phase 1: xp[b*T+t][j] = x[b,t,:] . W_ih[j,:] + b_ih[j], written to d_out.
// (unchanged, ~300us)
// ---------------------------------------------------------------------------
__global__ __launch_bounds__(256) void gemm_xp(const float* __restrict__ x,
                                               const float* __restrict__ Wih,
                                               const float* __restrict__ bih,
                                               float* __restrict__ out) {
    __shared__ alignas(16) _Float16 As[128 * 40];   // row stride 40 elems (80 B)
    __shared__ alignas(16) _Float16 Bs[128 * 40];

    const int tid  = threadIdx.x;
    const int bm   = blockIdx.x >> 3;              // 256 m-tiles
    const int bn   = blockIdx.x & 7;               // 8 n-tiles
    const int M0   = bm * 128, N0 = bn * 128;
    const int lane = tid & 63, w = tid >> 6;
    const int wm   = (w & 1) * 64, wn = (w >> 1) * 64;   // wave quadrant
    const int ro   = lane & 15, q = lane >> 4;
    const int sr   = tid >> 3, sc = tid & 7;       // staging: 32 rows x 8 chunks

    const f32x4 zero4 = {0.f, 0.f, 0.f, 0.f};
    f32x4 acc[4][4];
    #pragma unroll
    for (int i = 0; i < 4; ++i)
        #pragma unroll
        for (int j = 0; j < 4; ++j) acc[i][j] = zero4;

    for (int kk = 0; kk < 32; ++kk) {
        const int k0 = kk * 32;
        #pragma unroll
        for (int ir = 0; ir < 4; ++ir) {
            const int row = ir * 32 + sr;
            const float4 av = *(const float4*)(x   + (size_t)(M0 + row) * II_ + k0 + sc * 4);
            const float4 bv = *(const float4*)(Wih + (size_t)(N0 + row) * II_ + k0 + sc * 4);
            half4v ah = { (_Float16)av.x, (_Float16)av.y, (_Float16)av.z, (_Float16)av.w };
            half4v bh = { (_Float16)bv.x, (_Float16)bv.y, (_Float16)bv.z, (_Float16)bv.w };
            *(half4v*)(As + row * 40 + sc * 4) = ah;
            *(half4v*)(Bs + row * 40 + sc * 4) = bh;
        }
        __syncthreads();

        half8 a[4], b[4];
        #pragma unroll
        for (int i = 0; i < 4; ++i) {
            a[i] = *(const half8*)(As + (wm + i * 16 + ro) * 40 + q * 8);
            b[i] = *(const half8*)(Bs + (wn + i * 16 + ro) * 40 + q * 8);
        }
        #pragma unroll
        for (int i = 0; i < 4; ++i)
            #pragma unroll
            for (int j = 0; j < 4; ++j)
                acc[i][j] = __builtin_amdgcn_mfma_f32_16x16x32_f16(a[i], b[j], acc[i][j], 0, 0, 0);
        __syncthreads();
    }

    #pragma unroll
    for (int j = 0; j < 4; ++j) {
        const int col = N0 + wn + j * 16 + ro;
        const float bias = bih[col];
        #pragma unroll
        for (int i = 0; i < 4; ++i) {
            #pragma unroll
            for (int r = 0; r < 4; ++r) {
                const int rowg = M0 + wm + i * 16 + q * 4 + r;
                out[(size_t)rowg * HH_ + col] = acc[i][j][r] + bias;
            }
        }
    }
}

// ---------------------------------------------------------------------------
// Phase 2: persistent recurrence, restructured to fat WGs + full MFMA rows.
//
// 32 WGs x 512 threads = 4 independent groups x 8 WGs. A group owns 16
// batches (ALL 16 MFMA A-rows real -- no zero padding, 4x the output per
// MFMA vs r1..r3). Each WG owns 128 cols; wave w owns cols j0+16w..+15 with
// its full-K W_hh slice in VGPRs (wf[4][8] = 128 VGPRs). No cross-wave
// reduction; ONE __syncthreads per step (LDS double-buffered by parity).
//
// Sync protocol: byte-for-byte r1 (proven passing twice): comm word =
// {tag:16 | f16(h):16}, relaxed agent-scope stores/loads (coherence point =
// LLC). NO sc0-only stores (r2/r4 both hung: sc0 alone is SE scope, no
// visibility guarantee across SEs). Double-buffered by step parity; max
// producer/consumer skew is 1 step group-internally (posting H_{t+1}
// requires having read all of H_t, which requires every group member past
// step t-1 reads), so slot reuse at distance 2 never clobbers a live word.
// Poison 0xAAAA never matches tags 1..512. ws = 512 KB, r1 footprint.
//
// Why this beats r3 (theory): 1024 polling waves re-reading 4KB rounds
// saturated the LLC (~15 TB/s of poll traffic) and degree-16 convoy tails
// compounded 512x. Now: 256 polling waves, ~4x less poll traffic, degree 8.
// ---------------------------------------------------------------------------
__global__ __launch_bounds__(512, 2) void rnn_steps(const float* __restrict__ Whh,
                                                    const float* __restrict__ bhh,
                                                    const float* __restrict__ h0,
                                                    float* __restrict__ out,
                                                    unsigned* __restrict__ comm) {
    // [slot][batch 0..15][col]: f16 h, row stride 1032 (2064 B). 64.5 KB.
    __shared__ alignas(16) _Float16 hbuf[2][16][1032];

    const int tid  = threadIdx.x;
    const int lane = tid & 63;
    const int w    = tid >> 6;            // wave 0..7: owns 16 cols, stages 2 batch rows
    const int g    = blockIdx.x >> 3;     // group 0..3 (16 batches each)
    const int wg   = blockIdx.x & 7;      // wg within group: 128 cols
    const int b0   = g * 16;
    const int j0   = wg * 128;
    const int ro   = lane & 15, q = lane >> 4;
    const int col  = j0 + w * 16 + ro;    // this lane's output column

    // Preload W_hh B-fragments (full K): wf[kq][ks][e] = Whh[col][k],
    // n = ro, k = kq*256 + ks*32 + q*8 + e. 128 VGPRs.
    half8 wf[4][8];
    {
        const float* wrow = Whh + (size_t)col * HH_;
        #pragma unroll
        for (int kq = 0; kq < 4; ++kq) {
            #pragma unroll
            for (int ks = 0; ks < 8; ++ks) {
                const int kc = kq * 256 + ks * 32 + q * 8;
                const float4 w0 = *(const float4*)(wrow + kc);
                const float4 w1 = *(const float4*)(wrow + kc + 4);
                half8 hv;
                hv[0] = (_Float16)w0.x; hv[1] = (_Float16)w0.y;
                hv[2] = (_Float16)w0.z; hv[3] = (_Float16)w0.w;
                hv[4] = (_Float16)w1.x; hv[5] = (_Float16)w1.y;
                hv[6] = (_Float16)w1.z; hv[7] = (_Float16)w1.w;
                wf[kq][ks] = hv;
            }
        }
    }
    const float bhh_r = bhh[col];
    const f32x4 zero4 = {0.f, 0.f, 0.f, 0.f};

    #define TAGOK_(v) ((((unsigned)((v) >> 16) & 0xffffu) == su) & \
                       ((unsigned)((v) >> 48) == su))

    for (int s = 0; s < TT_; ++s) {
        const int slot = s & 1;

        // xp prefetch: 4 values per lane (batches q*4+r, col); issued first
        // so HBM latency (~900cy) hides under the poll + MFMA.
        float xpv[4];
        #pragma unroll
        for (int r = 0; r < 4; ++r)
            xpv[r] = out[((size_t)(b0 + q * 4 + r) * TT_ + s) * HH_ + col];

        // ---- stage h_s (input state) rows 2w, 2w+1 into hbuf[slot] ----
        unsigned* dst0 = (unsigned*)(&hbuf[slot][2 * w][0]);
        unsigned* dst1 = (unsigned*)(&hbuf[slot][2 * w + 1][0]);
        if (s == 0) {
            #pragma unroll
            for (int rr = 0; rr < 2; ++rr) {
                const float2* hrow = (const float2*)(h0 + (size_t)(b0 + 2 * w + rr) * HH_);
                unsigned* d = rr ? dst1 : dst0;
                #pragma unroll
                for (int c = 0; c < 8; ++c) {
                    const float2 hv = hrow[c * 64 + lane];
                    union { _Float16 h[2]; unsigned u; } pk;
                    pk.h[0] = (_Float16)hv.x; pk.h[1] = (_Float16)hv.y;
                    d[c * 64 + lane] = pk.u;
                }
            }
        } else {
            const unsigned su = (unsigned)s;
            const unsigned long long* sp0 = (const unsigned long long*)
                (comm + (size_t)slot * (BB_ * HH_) + (size_t)(b0 + 2 * w) * HH_);
            const unsigned long long* sp1 = (const unsigned long long*)
                (comm + (size_t)slot * (BB_ * HH_) + (size_t)(b0 + 2 * w + 1) * HH_);
            // poll 16 u64 (two full 4KB batch rows per wave); each 32-bit
            // half carries its own tag => tearing harmless. Reload only
            // stale entries (cuts steady-state poll bandwidth).
            unsigned long long v[16];
            #pragma unroll
            for (int i = 0; i < 16; ++i) v[i] = 0ull;
            bool ok = false;
            while (!ok) {
                ok = true;
                #pragma unroll
                for (int i = 0; i < 16; ++i) {
                    if (!TAGOK_(v[i])) {
                        const unsigned long long* sp = (i < 8) ? sp0 : sp1;
                        v[i] = __hip_atomic_load(sp + (i & 7) * 64 + lane,
                                                 __ATOMIC_RELAXED,
                                                 __HIP_MEMORY_SCOPE_AGENT);
                        ok = false;
                    }
                }
            }
            // pack two f16 halves -> one b32 LDS write (stride-4B, conflict-free)
            #define PACK_(x) ((unsigned)((x) & 0xffffull) | (((unsigned)((x) >> 32)) << 16))
            #pragma unroll
            for (int i = 0; i < 8; ++i)  dst0[i * 64 + lane] = PACK_(v[i]);
            #pragma unroll
            for (int i = 8; i < 16; ++i) dst1[(i - 8) * 64 + lane] = PACK_(v[i]);
            #undef PACK_
        }
        __syncthreads();   // the only barrier per step (LDS double-buffered)

        // ---- MFMA: 16 batches x 16 cols x K=1024; 4 independent k-chains
        f32x4 acc[4] = {zero4, zero4, zero4, zero4};
        const _Float16* abase = &hbuf[slot][0][0] + (size_t)ro * 1032;
        #pragma unroll
        for (int kq = 0; kq < 4; ++kq) {
            #pragma unroll
            for (int ks = 0; ks < 8; ++ks) {
                const half8 a = *(const half8*)(abase + kq * 256 + ks * 32 + q * 8);
                acc[kq] = __builtin_amdgcn_mfma_f32_16x16x32_f16(a, wf[kq][ks], acc[kq], 0, 0, 0);
            }
        }

        // ---- epilogue: D row = q*4+r (batch, ALL rows real), col = ro.
        // Every lane owns 4 (batch, col) outputs -- no redistribution.
        const f32x4 sum = acc[0] + acc[1] + acc[2] + acc[3];
        const unsigned tagn = (unsigned)(s + 1) << 16;
        unsigned* cbase = comm + (size_t)((s + 1) & 1) * (BB_ * HH_);
        float hn[4];
        // comm posts FIRST (inter-WG critical path), out stores after.
        #pragma unroll
        for (int r = 0; r < 4; ++r) {
            hn[r] = fast_tanh(xpv[r] + bhh_r + sum[r]);
            union { _Float16 h; unsigned short us; } cv; cv.h = (_Float16)hn[r];
            __hip_atomic_store(cbase + (size_t)(b0 + q * 4 + r) * HH_ + col,
                               tagn | (unsigned)cv.us, __ATOMIC_RELAXED,
                               __HIP_MEMORY_SCOPE_AGENT);
        }
        #pragma unroll
        for (int r = 0; r < 4; ++r)
            out[((size_t)(b0 + q * 4 + r) * TT_ + s) * HH_ + col] = hn[r];
        // no trailing barrier: next step stages into hbuf[slot^1]; reuse at
        // distance 2 is ordered by the step s+1 __syncthreads.
    }
    #undef TAGOK_
}

// ---------------------------------------------------------------------------
extern "C" void kernel_launch(void* const* d_in, const int* in_sizes, int n_in,
                              void* d_out, int out_size, void* d_ws, size_t ws_size,
                              hipStream_t stream) {
    (void)in_sizes; (void)n_in; (void)out_size; (void)ws_size;

    const float* x   = (const float*)d_in[0];
    const float* h0  = (const float*)d_in[1];
    const float* Wih = (const float*)d_in[2];
    const float* bih = (const float*)d_in[3];
    const float* Whh = (const float*)d_in[4];
    const float* bhh = (const float*)d_in[5];
    float* out = (float*)d_out;

    // d_ws: comm only -- 2 slots x 64 x 1024 u32 = 512 KB (r1-verified
    // footprint; no memset needed: poison tag 0xAAAA never matches 1..512).
    unsigned* comm = (unsigned*)d_ws;

    gemm_xp<<<2048, 256, 0, stream>>>(x, Wih, bih, out);
    rnn_steps<<<32, 512, 0, stream>>>(Whh, bhh, h0, out, comm);
}

// Round 6
// 1543.205 us; speedup vs baseline: 1.4804x; 1.4804x over previous
//
#include <hip/hip_runtime.h>
#include <hip/hip_bf16.h>

// Problem constants: B=64, T=512, I=1024, H=1024 (fp32 in/out).
#define BB_   64
#define TT_   512
#define II_   1024
#define HH_   1024

typedef _Float16 half8  __attribute__((ext_vector_type(8)));
typedef _Float16 half4v __attribute__((ext_vector_type(4)));
typedef float    f32x4  __attribute__((ext_vector_type(4)));

// tanh(x) = 1 - 2/(exp(2x)+1); clamp |x|<=16 (tanh saturates; avoids inf/inf).
// v_exp_f32 + v_rcp_f32: ~6 ops vs ocml tanhf's ~300cy chain. abs err ~1e-7,
// invisible vs the f16 comm rounding (absmax 0.0039, r1/r3/r5).
__device__ __forceinline__ float fast_tanh(float x) {
    float t = fminf(fmaxf(x, -16.f), 16.f);
    float e = __builtin_amdgcn_exp2f(t * 2.885390082f);   // exp(2t)
    return 1.f - 2.f * __builtin_amdgcn_rcpf(e + 1.f);
}

// ---------------------------------------------------------------------------
// Phase 1: xp[b*T+t][j] = x[b,t,:] . W_ih[j,:] + b_ih[j], written to d_out.
// (unchanged, ~320us)
// ---------------------------------------------------------------------------
__global__ __launch_bounds__(256) void gemm_xp(const float* __restrict__ x,
                                               const float* __restrict__ Wih,
                                               const float* __restrict__ bih,
                                               float* __restrict__ out) {
    __shared__ alignas(16) _Float16 As[128 * 40];   // row stride 40 elems (80 B)
    __shared__ alignas(16) _Float16 Bs[128 * 40];

    const int tid  = threadIdx.x;
    const int bm   = blockIdx.x >> 3;              // 256 m-tiles
    const int bn   = blockIdx.x & 7;               // 8 n-tiles
    const int M0   = bm * 128, N0 = bn * 128;
    const int lane = tid & 63, w = tid >> 6;
    const int wm   = (w & 1) * 64, wn = (w >> 1) * 64;   // wave quadrant
    const int ro   = lane & 15, q = lane >> 4;
    const int sr   = tid >> 3, sc = tid & 7;       // staging: 32 rows x 8 chunks

    const f32x4 zero4 = {0.f, 0.f, 0.f, 0.f};
    f32x4 acc[4][4];
    #pragma unroll
    for (int i = 0; i < 4; ++i)
        #pragma unroll
        for (int j = 0; j < 4; ++j) acc[i][j] = zero4;

    for (int kk = 0; kk < 32; ++kk) {
        const int k0 = kk * 32;
        #pragma unroll
        for (int ir = 0; ir < 4; ++ir) {
            const int row = ir * 32 + sr;
            const float4 av = *(const float4*)(x   + (size_t)(M0 + row) * II_ + k0 + sc * 4);
            const float4 bv = *(const float4*)(Wih + (size_t)(N0 + row) * II_ + k0 + sc * 4);
            half4v ah = { (_Float16)av.x, (_Float16)av.y, (_Float16)av.z, (_Float16)av.w };
            half4v bh = { (_Float16)bv.x, (_Float16)bv.y, (_Float16)bv.z, (_Float16)bv.w };
            *(half4v*)(As + row * 40 + sc * 4) = ah;
            *(half4v*)(Bs + row * 40 + sc * 4) = bh;
        }
        __syncthreads();

        half8 a[4], b[4];
        #pragma unroll
        for (int i = 0; i < 4; ++i) {
            a[i] = *(const half8*)(As + (wm + i * 16 + ro) * 40 + q * 8);
            b[i] = *(const half8*)(Bs + (wn + i * 16 + ro) * 40 + q * 8);
        }
        #pragma unroll
        for (int i = 0; i < 4; ++i)
            #pragma unroll
            for (int j = 0; j < 4; ++j)
                acc[i][j] = __builtin_amdgcn_mfma_f32_16x16x32_f16(a[i], b[j], acc[i][j], 0, 0, 0);
        __syncthreads();
    }

    #pragma unroll
    for (int j = 0; j < 4; ++j) {
        const int col = N0 + wn + j * 16 + ro;
        const float bias = bih[col];
        #pragma unroll
        for (int i = 0; i < 4; ++i) {
            #pragma unroll
            for (int r = 0; r < 4; ++r) {
                const int rowg = M0 + wm + i * 16 + q * 4 + r;
                out[(size_t)rowg * HH_ + col] = acc[i][j][r] + bias;
            }
        }
    }
}

// ---------------------------------------------------------------------------
// Phase 2: persistent recurrence -- the r1 structure (best measured: 1280us)
// with only the two r3-proven VALU wins grafted on (fast_tanh + all-lane
// epilogue) and comm-post-before-out-store ordering.
//
// 256 WGs x 256 thr = 16 groups (4 batches) x 16 WGs (64 cols). Wave w of a
// WG owns 16 cols x full K=1024 (W_hh slice in wf[4][8] = 128 VGPRs); no
// cross-wave reduction; ONE __syncthreads per step (LDS double-buffered).
//
// Sync: r1's tagged-word protocol verbatim. Comm word = {tag:16 | f16:16};
// relaxed agent-scope stores/loads only (coherence point = LLC). NO sc0-only
// anything (r2/r4 failed with sc0 producer stores; r3's sc0 poll fastpath
// measured +~120us vs r1 -- both retired). Double-buffered by step parity;
// max producer/consumer skew is 1 step (posting H_{t+1} requires having read
// all of H_t), so slot reuse at distance 2 never clobbers a live word.
// Poison tag 0xAAAA never matches real tags 1..512. ws = 512 KB exactly.
// ---------------------------------------------------------------------------
__global__ __launch_bounds__(256, 1) void rnn_steps(const float* __restrict__ Whh,
                                                    const float* __restrict__ bhh,
                                                    const float* __restrict__ h0,
                                                    float* __restrict__ out,
                                                    unsigned* __restrict__ comm) {
    // [slot][row][col]: rows 0..3 = batches (f16 h), row 4 = zeros (pads MFMA
    // A rows 4..15). Row stride 1032 f16 = 2064 B.
    __shared__ alignas(16) _Float16 hbuf[2][5][1032];

    const int tid  = threadIdx.x;
    const int lane = tid & 63;
    const int w    = tid >> 6;             // wave id: stages batch w, owns 16 cols
    const int g    = blockIdx.x >> 4;      // group 0..15
    const int wg   = blockIdx.x & 15;      // wg within group
    const int b0   = g * 4;
    const int j0   = wg * 64;
    const int ro   = lane & 15, q = lane >> 4;
    const int arow = (ro < 4) ? ro : 4;    // A rows >=4 read the shared zero row
    const int bat  = lane >> 4;            // epilogue: this lane's batch 0..3
    const int colw = j0 + w * 16 + (lane & 15);  // epilogue: this lane's column

    // Preload W_hh B-fragments (full K): wf[kq][ks][e] = Whh[n][k],
    // n = j0 + w*16 + ro, k = kq*256 + ks*32 + q*8 + e. 128 VGPRs.
    half8 wf[4][8];
    {
        const float* wrow = Whh + (size_t)(j0 + w * 16 + ro) * HH_;
        #pragma unroll
        for (int kq = 0; kq < 4; ++kq) {
            #pragma unroll
            for (int ks = 0; ks < 8; ++ks) {
                const int kc = kq * 256 + ks * 32 + q * 8;
                const float4 w0 = *(const float4*)(wrow + kc);
                const float4 w1 = *(const float4*)(wrow + kc + 4);
                half8 hv;
                hv[0] = (_Float16)w0.x; hv[1] = (_Float16)w0.y;
                hv[2] = (_Float16)w0.z; hv[3] = (_Float16)w0.w;
                hv[4] = (_Float16)w1.x; hv[5] = (_Float16)w1.y;
                hv[6] = (_Float16)w1.z; hv[7] = (_Float16)w1.w;
                wf[kq][ks] = hv;
            }
        }
    }
    const float bhh_r = bhh[colw];

    // zero row 4 of both LDS slots
    for (int i = tid; i < 1032; i += 256) {
        hbuf[0][4][i] = (_Float16)0.f;
        hbuf[1][4][i] = (_Float16)0.f;
    }

    const f32x4 zero4 = {0.f, 0.f, 0.f, 0.f};

    #define TAGOK_(v) ((((unsigned)((v) >> 16) & 0xffffu) == su) & \
                       ((unsigned)((v) >> 48) == su))

    for (int s = 0; s < TT_; ++s) {
        const int slot = s & 1;

        // xp prefetch: one value per lane (batch bat, col colw); issued first
        // so its latency hides under the poll.
        const float xpv = out[((size_t)(b0 + bat) * TT_ + s) * HH_ + colw];

        // ---- stage h_s into hbuf[slot][w][:] as packed f16 pairs ----
        unsigned* dstw = (unsigned*)(&hbuf[slot][w][0]);
        if (s == 0) {
            const float2* hrow = (const float2*)(h0 + (size_t)(b0 + w) * HH_);
            #pragma unroll
            for (int c = 0; c < 8; ++c) {
                const float2 hv = hrow[c * 64 + lane];
                union { _Float16 h[2]; unsigned u; } pk;
                pk.h[0] = (_Float16)hv.x; pk.h[1] = (_Float16)hv.y;
                dstw[c * 64 + lane] = pk.u;
            }
        } else {
            // poll own batch row (8 u64 per lane = 4KB per wave); each 32-bit
            // half carries its own tag => tearing harmless.
            const unsigned su = (unsigned)s;
            const unsigned long long* sp = (const unsigned long long*)
                (comm + (size_t)slot * (BB_ * HH_) + (size_t)(b0 + w) * HH_);
            unsigned long long v0, v1, v2, v3, v4, v5, v6, v7;
            bool ok = false;
            while (!ok) {
                v0 = __hip_atomic_load(sp + 0 * 64 + lane, __ATOMIC_RELAXED, __HIP_MEMORY_SCOPE_AGENT);
                v1 = __hip_atomic_load(sp + 1 * 64 + lane, __ATOMIC_RELAXED, __HIP_MEMORY_SCOPE_AGENT);
                v2 = __hip_atomic_load(sp + 2 * 64 + lane, __ATOMIC_RELAXED, __HIP_MEMORY_SCOPE_AGENT);
                v3 = __hip_atomic_load(sp + 3 * 64 + lane, __ATOMIC_RELAXED, __HIP_MEMORY_SCOPE_AGENT);
                v4 = __hip_atomic_load(sp + 4 * 64 + lane, __ATOMIC_RELAXED, __HIP_MEMORY_SCOPE_AGENT);
                v5 = __hip_atomic_load(sp + 5 * 64 + lane, __ATOMIC_RELAXED, __HIP_MEMORY_SCOPE_AGENT);
                v6 = __hip_atomic_load(sp + 6 * 64 + lane, __ATOMIC_RELAXED, __HIP_MEMORY_SCOPE_AGENT);
                v7 = __hip_atomic_load(sp + 7 * 64 + lane, __ATOMIC_RELAXED, __HIP_MEMORY_SCOPE_AGENT);
                bool o = true;
                o &= TAGOK_(v0); o &= TAGOK_(v1); o &= TAGOK_(v2); o &= TAGOK_(v3);
                o &= TAGOK_(v4); o &= TAGOK_(v5); o &= TAGOK_(v6); o &= TAGOK_(v7);
                ok = o;
            }
            // pack two f16 halves -> one b32 LDS write (stride-4B, conflict-free)
            #define PACK_(x) ((unsigned)((x) & 0xffffull) | (((unsigned)((x) >> 32)) << 16))
            dstw[0 * 64 + lane] = PACK_(v0);
            dstw[1 * 64 + lane] = PACK_(v1);
            dstw[2 * 64 + lane] = PACK_(v2);
            dstw[3 * 64 + lane] = PACK_(v3);
            dstw[4 * 64 + lane] = PACK_(v4);
            dstw[5 * 64 + lane] = PACK_(v5);
            dstw[6 * 64 + lane] = PACK_(v6);
            dstw[7 * 64 + lane] = PACK_(v7);
            #undef PACK_
        }
        __syncthreads();   // the only barrier per step (LDS double-buffered)

        // ---- MFMA: this wave's 16 cols x full K=1024, 4 independent chains
        f32x4 acc[4] = {zero4, zero4, zero4, zero4};
        const _Float16* abase = &hbuf[slot][0][0] + (size_t)arow * 1032;
        #pragma unroll
        for (int kq = 0; kq < 4; ++kq) {
            #pragma unroll
            for (int ks = 0; ks < 8; ++ks) {
                const half8 a = *(const half8*)(abase + kq * 256 + ks * 32 + q * 8);
                acc[kq] = __builtin_amdgcn_mfma_f32_16x16x32_f16(a, wf[kq][ks], acc[kq], 0, 0, 0);
            }
        }

        // ---- epilogue, all 64 lanes (r3-proven): redistribute D (row =
        // batch on q==0 lanes, col = lane&15) so each lane owns one
        // (batch, col) value -> 1 tanh + 2 stores per lane.
        const f32x4 sum = acc[0] + acc[1] + acc[2] + acc[3];
        const float t0 = __shfl(sum[0], lane & 15);
        const float t1 = __shfl(sum[1], lane & 15);
        const float t2 = __shfl(sum[2], lane & 15);
        const float t3 = __shfl(sum[3], lane & 15);
        const float val = (bat == 0) ? t0 : (bat == 1) ? t1 : (bat == 2) ? t2 : t3;

        const float hnew = fast_tanh(xpv + bhh_r + val);

        // tagged comm word FIRST (inter-WG critical path), out store after.
        union { _Float16 h; unsigned short us; } cv; cv.h = (_Float16)hnew;
        const unsigned word = ((unsigned)(s + 1) << 16) | (unsigned)cv.us;
        __hip_atomic_store(comm + (size_t)((s + 1) & 1) * (BB_ * HH_)
                                + (size_t)(b0 + bat) * HH_ + colw,
                           word, __ATOMIC_RELAXED, __HIP_MEMORY_SCOPE_AGENT);

        out[((size_t)(b0 + bat) * TT_ + s) * HH_ + colw] = hnew;
        // no trailing barrier: next step stages into hbuf[slot^1]; reuse at
        // distance 2 is ordered by the step s+1 __syncthreads.
    }
    #undef TAGOK_
}

// ---------------------------------------------------------------------------
extern "C" void kernel_launch(void* const* d_in, const int* in_sizes, int n_in,
                              void* d_out, int out_size, void* d_ws, size_t ws_size,
                              hipStream_t stream) {
    (void)in_sizes; (void)n_in; (void)out_size; (void)ws_size;

    const float* x   = (const float*)d_in[0];
    const float* h0  = (const float*)d_in[1];
    const float* Wih = (const float*)d_in[2];
    const float* bih = (const float*)d_in[3];
    const float* Whh = (const float*)d_in[4];
    const float* bhh = (const float*)d_in[5];
    float* out = (float*)d_out;

    // d_ws: comm only -- 2 slots x 64 x 1024 u32 = 512 KB (r1-verified
    // footprint; no memset needed: poison tag 0xAAAA never matches 1..512).
    unsigned* comm = (unsigned*)d_ws;

    gemm_xp<<<2048, 256, 0, stream>>>(x, Wih, bih, out);
    rnn_steps<<<256, 256, 0, stream>>>(Whh, bhh, h0, out, comm);
}